// Round 6
// baseline (170.416 us; speedup 1.0000x reference)
//
#include <hip/hip_runtime.h>
#include <math.h>

// Problem constants
#define B64 64
#define IN_SH 10000
#define GOSLD 10240         // gos bf16 padded leading dim (zero pad), mult of 32
#define EXP_SH 53
#define HID 1500
#define NPAD1 1536          // padded N for gemm1 accumulator
#define NBC 2048
#define K2 1553
#define XLD 1664            // X bf16 padded leading dim (13*128), zero padded
#define KS1 40              // split-K chunks gemm1 (960 gemm blocks)
#define KCH1 256            // k per chunk = KST1*32
#define KST1 8
#define KS2 13
#define KCH2 128            // = KST2*32
#define KST2 4
#define CMCH 32             // colmax row chunks
#define G1BLKS (24 * KS1)   // 960

using short8  = __attribute__((ext_vector_type(8))) short;
using floatx4 = __attribute__((ext_vector_type(4))) float;
using uintx4  = __attribute__((ext_vector_type(4))) unsigned int;

__device__ __forceinline__ unsigned short f2bf(float f) {
    unsigned u = __float_as_uint(f);
    u += 0x7fffu + ((u >> 16) & 1u);   // RNE
    return (unsigned short)(u >> 16);
}

// Node 1: [0,320) gos fp32->bf16 pad; [320,328) zero fp32 accumulators (hpre+logits).
__global__ __launch_bounds__(256) void prep_k(const float* __restrict__ g,
                                              unsigned short* __restrict__ gb,
                                              float* __restrict__ accz) {
    int bi = blockIdx.x;
    if (bi < 320) {
        int idx = bi * 256 + threadIdx.x;          // 64*1280 threads
        int b = idx / (GOSLD / 8);
        int k = (idx % (GOSLD / 8)) * 8;
        unsigned int o[4] = {0u, 0u, 0u, 0u};
        if (k < IN_SH) {
            const float* p = g + (size_t)b * IN_SH + k;
            #pragma unroll
            for (int i = 0; i < 4; i++) {
                float lo = p[2 * i], hi = p[2 * i + 1];
                o[i] = (unsigned)f2bf(lo) | ((unsigned)f2bf(hi) << 16);
            }
        }
        uintx4 v; v.x = o[0]; v.y = o[1]; v.z = o[2]; v.w = o[3];
        *(uintx4*)(gb + (size_t)b * GOSLD + k) = v;
    } else {
        // zero 229376 floats with 8 blocks: 2048 threads * 28 float4
        int t = (bi - 320) * 256 + threadIdx.x;    // 0..2047
        floatx4 z = (floatx4){0.f, 0.f, 0.f, 0.f};
        #pragma unroll
        for (int i = 0; i < 28; i++)
            *(floatx4*)(accz + (size_t)(i * 2048 + t) * 4) = z;
    }
}

// one pipeline stage's loads: W column slice (fp32, strided) + activation rows (bf16 x8)
__device__ __forceinline__ void load_step(
    const float* __restrict__ W, const unsigned short* __restrict__ brow0,
    int kb, int K, int ldw, int ldb, int cW, bool nok,
    float wv[8], uintx4 bv[4])
{
    #pragma unroll
    for (int j = 0; j < 8; j++) {
        int k = kb + j;
        wv[j] = (nok && k < K) ? W[(size_t)k * ldw + cW] : 0.f;
    }
    #pragma unroll
    for (int s = 0; s < 4; s++)
        bv[s] = *(const uintx4*)(brow0 + (size_t)s * 16 * ldb + kb);
}

// Direct-streaming MFMA GEMM core, no LDS, no barriers, depth-2 prefetch,
// fp32 atomicAdd accumulation into accbuf[n*64+b].
// KSTEPS compile-time: full unroll keeps double-buffer arrays in VGPRs
// (runtime index caused 149 MB of scratch spill in round 3).
template<int KSTEPS>
__device__ __forceinline__ void gemm_core(
    const float* __restrict__ W, const unsigned short* __restrict__ Bm,
    float* __restrict__ accbuf, int N, int K, int ldw, int ldb, int kchunk,
    int bx, int by, int tid)
{
    int w    = tid >> 6;
    int lane = tid & 63;
    int q    = lane >> 4;
    int l15  = lane & 15;
    int n0   = bx * 64;
    int k0   = by * kchunk;
    int cW   = n0 + 16 * w + l15;      // W column this lane reads (A-frag m index)
    bool nok = cW < N;
    int qk   = q * 8;

    floatx4 acc[4];
    #pragma unroll
    for (int s = 0; s < 4; s++) acc[s] = (floatx4){0.f, 0.f, 0.f, 0.f};

    const unsigned short* brow0 = Bm + (size_t)l15 * ldb;

    float  wv[2][8];
    uintx4 bv[2][4];
    load_step(W, brow0, k0 + qk, K, ldw, ldb, cW, nok, wv[0], bv[0]);
    if (KSTEPS > 1)
        load_step(W, brow0, k0 + 32 + qk, K, ldw, ldb, cW, nok, wv[1], bv[1]);

    #pragma unroll
    for (int st = 0; st < KSTEPS; st++) {
        const int p = st & 1;                       // compile-time after unroll
        float  wt[8];
        uintx4 bt[4];
        if (st + 2 < KSTEPS)
            load_step(W, brow0, k0 + (st + 2) * 32 + qk, K, ldw, ldb, cW, nok, wt, bt);

        short8 af;
        #pragma unroll
        for (int j = 0; j < 8; j++) af[j] = (short)f2bf(wv[p][j]);
        #pragma unroll
        for (int s = 0; s < 4; s++) {
            short8 bf8 = __builtin_bit_cast(short8, bv[p][s]);
            acc[s] = __builtin_amdgcn_mfma_f32_16x16x32_bf16(af, bf8, acc[s], 0, 0, 0);
        }

        if (st + 2 < KSTEPS) {
            #pragma unroll
            for (int j = 0; j < 8; j++) wv[p][j] = wt[j];
            #pragma unroll
            for (int s = 0; s < 4; s++) bv[p][s] = bt[s];
        }
    }

    // D lane mapping: col=lane&15 (batch), row=q*4+r (n offset within 16)
    int nrow = n0 + 16 * w + q * 4;
    #pragma unroll
    for (int s = 0; s < 4; s++) {
        #pragma unroll
        for (int r = 0; r < 4; r++)
            atomicAdd(&accbuf[(size_t)(nrow + r) * 64 + s * 16 + l15], acc[s][r]);
    }
}

// Node 2: [0,960) GEMM1 split-K blocks; [960,1216) hpo partial column-max.
// No ordering dependency between the two halves (cm is consumed by final_k).
__global__ __launch_bounds__(256) void gemm1_k(
    const float* __restrict__ W1, const unsigned short* __restrict__ gosB,
    float* __restrict__ hpre, const float* __restrict__ M, float* __restrict__ cm)
{
    int bi = blockIdx.x;
    if (bi < G1BLKS) {
        gemm_core<KST1>(W1, gosB, hpre, HID, IN_SH, HID, GOSLD, KCH1,
                        bi % 24, bi / 24, threadIdx.x);
    } else {
        int ci = bi - G1BLKS;                       // 256 blocks: 8 j-tiles x 32 row-chunks
        int j  = (ci & 7) * 256 + threadIdx.x;      // 0..2047
        int i0 = (ci >> 3) * 64;
        float m = 0.0f;
        #pragma unroll 16
        for (int i = i0; i < i0 + 64; i++)
            m = fmaxf(m, M[(size_t)i * NBC + j]);
        cm[(ci >> 3) * NBC + j] = m;
    }
}

// Node 4: GEMM2
__global__ __launch_bounds__(256) void gemm2_k(
    const float* __restrict__ W2, const unsigned short* __restrict__ X,
    float* __restrict__ logits)
{
    gemm_core<KST2>(W2, X, logits, NBC, K2, NBC, XLD, KCH2,
                    blockIdx.x, blockIdx.y, threadIdx.x);
}

// Node 3: bias + exact GELU on h_pre -> X bf16 [64][XLD] (concat exp_x, zero pad)
__global__ __launch_bounds__(256) void combine1(
    const float* __restrict__ hpre, const float* __restrict__ b1,
    const float* __restrict__ expx, unsigned short* __restrict__ X)
{
    int idx = blockIdx.x * 256 + threadIdx.x;   // 64*1664 threads
    int b = idx & 63;
    int n = idx >> 6;
    float v = 0.f;
    if (n < HID) {
        float s = hpre[(size_t)n * 64 + b] + b1[n];
        v = 0.5f * s * (1.0f + erff(s * 0.70710678118654752f));
    } else if (n < HID + EXP_SH) {
        v = expx[b * EXP_SH + (n - HID)];
    }
    X[(size_t)b * XLD + n] = f2bf(v);
}

// Node 5: bias + sigmoid on logits, multiply by column max (reduced from 32 chunks)
__global__ __launch_bounds__(256) void final_k(
    const float* __restrict__ logits, const float* __restrict__ b2,
    const float* __restrict__ cm, float* __restrict__ out)
{
    int idx = blockIdx.x * 256 + threadIdx.x;   // 64*2048 threads
    int b = idx & 63;
    int j = idx >> 6;
    float s = logits[(size_t)j * 64 + b] + b2[j];
    float sig = 1.0f / (1.0f + expf(-s));
    float m = 0.f;
    #pragma unroll
    for (int c = 0; c < CMCH; c++) m = fmaxf(m, cm[c * NBC + j]);
    out[(size_t)b * NBC + j] = sig * m;
}

extern "C" void kernel_launch(void* const* d_in, const int* in_sizes, int n_in,
                              void* d_out, int out_size, void* d_ws, size_t ws_size,
                              hipStream_t stream) {
    const float* gos  = (const float*)d_in[0];
    const float* expx = (const float*)d_in[1];
    const float* W1   = (const float*)d_in[2];
    const float* b1   = (const float*)d_in[3];
    const float* W2   = (const float*)d_in[4];
    const float* b2   = (const float*)d_in[5];
    const float* hpo  = (const float*)d_in[6];
    float* out = (float*)d_out;

    // workspace layout (16B-aligned offsets)
    char* ws = (char*)d_ws;
    unsigned short* gosB = (unsigned short*)ws;                    // 64*10240*2 = 1,310,720
    float* hpre   = (float*)(ws + 1310720);                        // 1536*64*4  =   393,216
    float* logits = (float*)(ws + 1310720 + 393216);               // 2048*64*4  =   524,288  (contiguous with hpre)
    unsigned short* X = (unsigned short*)(ws + 1310720 + 393216 + 524288);   // 64*1664*2 = 212,992
    float* cm = (float*)(ws + 1310720 + 393216 + 524288 + 212992); // 32*2048*4  =   262,144
    // total ~2.7 MB

    // 1) gos->bf16 | zero accumulators
    prep_k<<<328, 256, 0, stream>>>(gos, gosB, hpre);

    // 2) GEMM1 (atomic split-K) fused with hpo column-max streaming
    gemm1_k<<<G1BLKS + 256, 256, 0, stream>>>(W1, gosB, hpre, hpo, cm);

    // 3) bias + gelu + concat exp_x -> X (bf16)
    combine1<<<(B64 * XLD) / 256, 256, 0, stream>>>(hpre, b1, expx, X);

    // 4) GEMM2: logits += X @ W2  (N=2048, K=1553), atomic split-K
    gemm2_k<<<dim3(NBC / 64, KS2), 256, 0, stream>>>(W2, X, logits);

    // 5) bias + sigmoid + *colmax -> out
    final_k<<<(B64 * NBC) / 256, 256, 0, stream>>>(logits, b2, cm, out);
}

// Round 7
// 162.660 us; speedup vs baseline: 1.0477x; 1.0477x over previous
//
#include <hip/hip_runtime.h>
#include <math.h>

// Problem constants
#define B64 64
#define IN_SH 10000
#define EXP_SH 53
#define HID 1500
#define NPAD1 1536          // padded N for gemm1 accumulator
#define NBC 2048
#define K2 1553
#define KS1 40              // split-K chunks gemm1 (24*40 = 960 blocks)
#define KST1 8              // 8 steps of 32 => kchunk 256
#define KS2 13              // 32*13 = 416 blocks
#define KST2 4              // 4 steps of 32 => kchunk 128
#define NSTEP1 320          // gosBf k-steps (10240/32)
#define NSTEP2 52           // Xf k-steps (1664/32)
#define CMCH 32             // colmax row chunks

using short8  = __attribute__((ext_vector_type(8))) short;
using floatx4 = __attribute__((ext_vector_type(4))) float;
using uintx4  = __attribute__((ext_vector_type(4))) unsigned int;

__device__ __forceinline__ unsigned short f2bf(float f) {
    unsigned u = __float_as_uint(f);
    u += 0x7fffu + ((u >> 16) & 1u);   // RNE
    return (unsigned short)(u >> 16);
}

// B-fragment-order activation buffer:
//   Bf[((step*4 + sgrp)*64 + lane)*8 + j] = act[b = sgrp*16 + (lane&15)][k = step*32 + (lane>>4)*8 + j]
// One contiguous 1KB dwordx4 load per (step, sgrp), shared by every wave/block.

// Node 1: [0,320) build gosBf; [320,576) hpo partial column max; [576,584) zero accumulators.
__global__ __launch_bounds__(256) void prep_k(const float* __restrict__ g,
                                              unsigned short* __restrict__ gosBf,
                                              const float* __restrict__ M,
                                              float* __restrict__ cm,
                                              float* __restrict__ accz) {
    int bi = blockIdx.x;
    if (bi < 320) {
        int t    = bi * 256 + threadIdx.x;   // [0, 81920)
        int lane = t & 63;
        int sgrp = (t >> 6) & 3;
        int step = t >> 8;                   // [0, 320)
        int q    = lane >> 4;
        int l15  = lane & 15;
        int b    = sgrp * 16 + l15;
        int k0   = step * 32 + q * 8;
        const float* p = g + (size_t)b * IN_SH + k0;
        unsigned int o[4];
        #pragma unroll
        for (int i = 0; i < 4; i++) {
            float lo = (k0 + 2 * i     < IN_SH) ? p[2 * i]     : 0.f;
            float hi = (k0 + 2 * i + 1 < IN_SH) ? p[2 * i + 1] : 0.f;
            o[i] = (unsigned)f2bf(lo) | ((unsigned)f2bf(hi) << 16);
        }
        uintx4 v; v.x = o[0]; v.y = o[1]; v.z = o[2]; v.w = o[3];
        *(uintx4*)(gosBf + (size_t)t * 8) = v;
    } else if (bi < 576) {
        int ci = bi - 320;                    // 256 blocks: 8 j-tiles x 32 row-chunks
        int j  = (ci & 7) * 256 + threadIdx.x;
        int i0 = (ci >> 3) * 64;
        float m = 0.0f;
        #pragma unroll 16
        for (int i = i0; i < i0 + 64; i++)
            m = fmaxf(m, M[(size_t)i * NBC + j]);
        cm[(ci >> 3) * NBC + j] = m;
    } else {
        // zero 229376 floats (hpre + logits contiguous): 8 blocks * 256 thr * 28 float4
        int t = (bi - 576) * 256 + threadIdx.x;
        floatx4 z = (floatx4){0.f, 0.f, 0.f, 0.f};
        #pragma unroll
        for (int i = 0; i < 28; i++)
            *(floatx4*)(accz + (size_t)(i * 2048 + t) * 4) = z;
    }
}

__device__ __forceinline__ void load_w8(const float* __restrict__ W, int kb, int K,
                                        int ldw, int cW, bool nok, float wv[8]) {
    #pragma unroll
    for (int j = 0; j < 8; j++) {
        int k = kb + j;
        wv[j] = (nok && k < K) ? W[(size_t)k * ldw + cW] : 0.f;
    }
}
__device__ __forceinline__ void load_b4(const unsigned short* __restrict__ bf,
                                        int stg, uintx4 bv[4]) {
    #pragma unroll
    for (int s = 0; s < 4; s++)
        bv[s] = *(const uintx4*)(bf + (size_t)(stg * 4 + s) * 512);
}

// Direct-streaming MFMA GEMM core: no LDS, no barriers, depth-3 prefetch,
// fp32 atomicAdd accumulation into accbuf[n*64+b].
// All pipeline-slot indices are compile-time (full unroll) -> stays in VGPRs.
template<int KSTEPS>
__device__ __forceinline__ void gemm_core(
    const float* __restrict__ W, const unsigned short* __restrict__ Bf,
    float* __restrict__ accbuf, int N, int K, int ldw, int bx, int by, int tid)
{
    int w    = tid >> 6;
    int lane = tid & 63;
    int q    = lane >> 4;
    int l15  = lane & 15;
    int n0   = bx * 64;
    int k0   = by * (KSTEPS * 32);
    int cW   = n0 + 16 * w + l15;      // W column this lane reads (A-frag m index)
    bool nok = cW < N;
    int qk   = q * 8;

    const unsigned short* bf = Bf + (size_t)(by * KSTEPS * 4) * 512 + (size_t)lane * 8;

    floatx4 acc[4];
    #pragma unroll
    for (int s = 0; s < 4; s++) acc[s] = (floatx4){0.f, 0.f, 0.f, 0.f};

    float  wv[3][8];
    uintx4 bv[3][4];
    #pragma unroll
    for (int d = 0; d < 3; d++) {
        int st = (d < KSTEPS) ? d : KSTEPS - 1;
        load_w8(W, k0 + st * 32 + qk, K, ldw, cW, nok, wv[d]);
        load_b4(bf, st, bv[d]);
    }

    #pragma unroll
    for (int st = 0; st < KSTEPS; st++) {
        const int p = st % 3;                       // compile-time after unroll
        float  wt[8];
        uintx4 bt[4];
        if (st + 3 < KSTEPS) {
            load_w8(W, k0 + (st + 3) * 32 + qk, K, ldw, cW, nok, wt);
            load_b4(bf, st + 3, bt);
        }

        short8 af;
        #pragma unroll
        for (int j = 0; j < 8; j++) af[j] = (short)f2bf(wv[p][j]);
        #pragma unroll
        for (int s = 0; s < 4; s++) {
            short8 bf8 = __builtin_bit_cast(short8, bv[p][s]);
            acc[s] = __builtin_amdgcn_mfma_f32_16x16x32_bf16(af, bf8, acc[s], 0, 0, 0);
        }

        if (st + 3 < KSTEPS) {
            #pragma unroll
            for (int j = 0; j < 8; j++) wv[p][j] = wt[j];
            #pragma unroll
            for (int s = 0; s < 4; s++) bv[p][s] = bt[s];
        }
    }

    // D lane mapping: col=lane&15 (batch within group s), row=q*4+r (n offset)
    int nrow = n0 + 16 * w + q * 4;
    #pragma unroll
    for (int s = 0; s < 4; s++) {
        #pragma unroll
        for (int r = 0; r < 4; r++)
            atomicAdd(&accbuf[(size_t)(nrow + r) * 64 + s * 16 + l15], acc[s][r]);
    }
}

// Node 2: GEMM1  h_pre += gos @ W1  (N=1500, K=10000)
__global__ __launch_bounds__(256) void gemm1_k(
    const float* __restrict__ W1, const unsigned short* __restrict__ gosBf,
    float* __restrict__ hpre)
{
    gemm_core<KST1>(W1, gosBf, hpre, HID, IN_SH, HID, blockIdx.x, blockIdx.y, threadIdx.x);
}

// Node 4: GEMM2  logits += X @ W2  (N=2048, K=1553)
__global__ __launch_bounds__(256) void gemm2_k(
    const float* __restrict__ W2, const unsigned short* __restrict__ Xf,
    float* __restrict__ logits)
{
    gemm_core<KST2>(W2, Xf, logits, NBC, K2, NBC, blockIdx.x, blockIdx.y, threadIdx.x);
}

// Node 3: bias + exact GELU on h_pre, concat exp_x, emit Xf in B-fragment order.
__global__ __launch_bounds__(256) void combine1(
    const float* __restrict__ hpre, const float* __restrict__ b1,
    const float* __restrict__ expx, unsigned short* __restrict__ Xf)
{
    int t    = blockIdx.x * 256 + threadIdx.x;   // [0, 13312)
    int lane = t & 63;
    int sgrp = (t >> 6) & 3;
    int step = t >> 8;                            // [0, 52)
    int q    = lane >> 4;
    int l15  = lane & 15;
    int b    = sgrp * 16 + l15;
    int kb   = step * 32 + q * 8;
    unsigned int o[4];
    #pragma unroll
    for (int i = 0; i < 4; i++) {
        unsigned int lohi[2];
        #pragma unroll
        for (int h = 0; h < 2; h++) {
            int n = kb + 2 * i + h;
            float v = 0.f;
            if (n < HID) {
                float s = hpre[(size_t)n * 64 + b] + b1[n];
                v = 0.5f * s * (1.0f + erff(s * 0.70710678118654752f));
            } else if (n < HID + EXP_SH) {
                v = expx[b * EXP_SH + (n - HID)];
            }
            lohi[h] = f2bf(v);
        }
        o[i] = lohi[0] | (lohi[1] << 16);
    }
    uintx4 v; v.x = o[0]; v.y = o[1]; v.z = o[2]; v.w = o[3];
    *(uintx4*)(Xf + (size_t)t * 8) = v;
}

// Node 5: bias + sigmoid on logits, multiply by column max (reduce 32 chunks)
__global__ __launch_bounds__(256) void final_k(
    const float* __restrict__ logits, const float* __restrict__ b2,
    const float* __restrict__ cm, float* __restrict__ out)
{
    int idx = blockIdx.x * 256 + threadIdx.x;   // 64*2048 threads
    int b = idx & 63;
    int j = idx >> 6;
    float s = logits[(size_t)j * 64 + b] + b2[j];
    float sig = 1.0f / (1.0f + expf(-s));
    float m = 0.f;
    #pragma unroll
    for (int c = 0; c < CMCH; c++) m = fmaxf(m, cm[c * NBC + j]);
    out[(size_t)b * NBC + j] = sig * m;
}

extern "C" void kernel_launch(void* const* d_in, const int* in_sizes, int n_in,
                              void* d_out, int out_size, void* d_ws, size_t ws_size,
                              hipStream_t stream) {
    const float* gos  = (const float*)d_in[0];
    const float* expx = (const float*)d_in[1];
    const float* W1   = (const float*)d_in[2];
    const float* b1   = (const float*)d_in[3];
    const float* W2   = (const float*)d_in[4];
    const float* b2   = (const float*)d_in[5];
    const float* hpo  = (const float*)d_in[6];
    float* out = (float*)d_out;

    // workspace layout (16B-aligned offsets)
    char* ws = (char*)d_ws;
    unsigned short* gosBf = (unsigned short*)ws;                   // 320*4*64*8*2 = 1,310,720
    float* hpre   = (float*)(ws + 1310720);                        // 1536*64*4    =   393,216
    float* logits = (float*)(ws + 1310720 + 393216);               // 2048*64*4    =   524,288 (contiguous with hpre)
    unsigned short* Xf = (unsigned short*)(ws + 1310720 + 393216 + 524288);  // 52*4*64*8*2 = 212,992
    float* cm = (float*)(ws + 1310720 + 393216 + 524288 + 212992); // 32*2048*4    =   262,144
    // total ~2.7 MB

    // 1) build gosBf | hpo partial column-max | zero accumulators
    prep_k<<<584, 256, 0, stream>>>(gos, gosBf, hpo, cm, hpre);

    // 2) GEMM1 (atomic split-K)
    gemm1_k<<<dim3(NPAD1 / 64, KS1), 256, 0, stream>>>(W1, gosBf, hpre);

    // 3) bias + gelu + concat exp_x -> Xf (B-fragment order)
    combine1<<<52, 256, 0, stream>>>(hpre, b1, expx, Xf);

    // 4) GEMM2 (atomic split-K)
    gemm2_k<<<dim3(NBC / 64, KS2), 256, 0, stream>>>(W2, Xf, logits);

    // 5) bias + sigmoid + *colmax -> out
    final_k<<<(B64 * NBC) / 256, 256, 0, stream>>>(logits, b2, cm, out);
}

// Round 8
// 162.374 us; speedup vs baseline: 1.0495x; 1.0018x over previous
//
#include <hip/hip_runtime.h>
#include <math.h>

// Problem constants
#define B64 64
#define IN_SH 10000
#define EXP_SH 53
#define HID 1500
#define NPAD1 1536          // padded N for gemm1 accumulator
#define NBC 2048
#define K2 1553
#define KS1 40              // split-K chunks gemm1 (24*40 = 960 blocks)
#define KST1 8              // 8 steps of 32 => kchunk 256
#define KS2 13              // 32*13 = 416 blocks
#define KST2 4              // 4 steps of 32 => kchunk 128
#define CMCH 32             // colmax row chunks
#define LDSF 2080           // 32 rows * 65 floats (pad +1 breaks conflicts)

using short8  = __attribute__((ext_vector_type(8))) short;
using floatx4 = __attribute__((ext_vector_type(4))) float;
using uintx4  = __attribute__((ext_vector_type(4))) unsigned int;

__device__ __forceinline__ unsigned short f2bf(float f) {
    unsigned u = __float_as_uint(f);
    u += 0x7fffu + ((u >> 16) & 1u);   // RNE
    return (unsigned short)(u >> 16);
}

// B-fragment-order activation buffer:
//   Bf[((step*4 + sgrp)*64 + lane)*8 + j] = act[b = sgrp*16 + (lane&15)][k = step*32 + (lane>>4)*8 + j]

// Node 1: [0,320) build gosBf; [320,576) hpo partial column max; [576,584) zero accumulators.
__global__ __launch_bounds__(256) void prep_k(const float* __restrict__ g,
                                              unsigned short* __restrict__ gosBf,
                                              const float* __restrict__ M,
                                              float* __restrict__ cm,
                                              float* __restrict__ accz) {
    int bi = blockIdx.x;
    if (bi < 320) {
        int t    = bi * 256 + threadIdx.x;   // [0, 81920)
        int lane = t & 63;
        int sgrp = (t >> 6) & 3;
        int step = t >> 8;                   // [0, 320)
        int q    = lane >> 4;
        int l15  = lane & 15;
        int b    = sgrp * 16 + l15;
        int k0   = step * 32 + q * 8;
        const float* p = g + (size_t)b * IN_SH + k0;
        unsigned int o[4];
        #pragma unroll
        for (int i = 0; i < 4; i++) {
            float lo = (k0 + 2 * i     < IN_SH) ? p[2 * i]     : 0.f;
            float hi = (k0 + 2 * i + 1 < IN_SH) ? p[2 * i + 1] : 0.f;
            o[i] = (unsigned)f2bf(lo) | ((unsigned)f2bf(hi) << 16);
        }
        uintx4 v; v.x = o[0]; v.y = o[1]; v.z = o[2]; v.w = o[3];
        *(uintx4*)(gosBf + (size_t)t * 8) = v;
    } else if (bi < 576) {
        int ci = bi - 320;                    // 256 blocks: 8 j-tiles x 32 row-chunks
        int j  = (ci & 7) * 256 + threadIdx.x;
        int i0 = (ci >> 3) * 64;
        float m = 0.0f;
        #pragma unroll 16
        for (int i = i0; i < i0 + 64; i++)
            m = fmaxf(m, M[(size_t)i * NBC + j]);
        cm[(ci >> 3) * NBC + j] = m;
    } else {
        // zero 229376 floats (hpre + logits contiguous): 8 blocks * 256 thr * 28 float4
        int t = (bi - 576) * 256 + threadIdx.x;
        floatx4 z = (floatx4){0.f, 0.f, 0.f, 0.f};
        #pragma unroll
        for (int i = 0; i < 28; i++)
            *(floatx4*)(accz + (size_t)(i * 2048 + t) * 4) = z;
    }
}

__device__ __forceinline__ void load_b4(const unsigned short* __restrict__ bf,
                                        int stg, uintx4 bv[4]) {
    #pragma unroll
    for (int s = 0; s < 4; s++)
        bv[s] = *(const uintx4*)(bf + (size_t)(stg * 4 + s) * 512);
}

// stage one 32k x 64n W patch into registers (coalesced dwordx4 rows; guarded on edge)
__device__ __forceinline__ void stage_load(
    const float* __restrict__ W, int kg0, int n0, int N, int K, int ldw,
    int tid, bool fast, float r[2][4])
{
    #pragma unroll
    for (int i = 0; i < 2; i++) {
        int kl = (tid >> 4) + 16 * i;          // row 0..31
        int kg = kg0 + kl;
        int n  = n0 + (tid & 15) * 4;
        if (fast) {
            floatx4 v = *(const floatx4*)(W + (size_t)kg * ldw + n);
            r[i][0] = v.x; r[i][1] = v.y; r[i][2] = v.z; r[i][3] = v.w;
        } else {
            #pragma unroll
            for (int j = 0; j < 4; j++)
                r[i][j] = (kg < K && n + j < N) ? W[(size_t)kg * ldw + n + j] : 0.f;
        }
    }
}

__device__ __forceinline__ void stage_write(float* __restrict__ ldsb, int tid,
                                            const float r[2][4]) {
    #pragma unroll
    for (int i = 0; i < 2; i++) {
        int kl  = (tid >> 4) + 16 * i;
        int seg = tid & 15;
        floatx4 v; v.x = r[i][0]; v.y = r[i][1]; v.z = r[i][2]; v.w = r[i][3];
        *(floatx4*)(ldsb + kl * 65 + seg * 4) = v;
    }
}

// LDS-staged MFMA GEMM core: coalesced W staging -> LDS double buffer (1 barrier/step),
// B-activations from fragment-order global buffer (depth-2 regs),
// fp32 atomicAdd accumulation into accbuf[n*64+b].
template<int KSTEPS>
__device__ __forceinline__ void gemm_core(
    const float* __restrict__ W, const unsigned short* __restrict__ Bf,
    float* __restrict__ accbuf, int N, int K, int ldw, int bx, int by, int tid,
    float (*lds)[LDSF])
{
    int w    = tid >> 6;
    int lane = tid & 63;
    int q    = lane >> 4;
    int l15  = lane & 15;
    int n0   = bx * 64;
    int k0   = by * (KSTEPS * 32);
    bool fast = (n0 + 64 <= N) && (k0 + KSTEPS * 32 <= K);

    const unsigned short* bf = Bf + (size_t)(by * KSTEPS * 4) * 512 + (size_t)lane * 8;

    floatx4 acc[4];
    #pragma unroll
    for (int s = 0; s < 4; s++) acc[s] = (floatx4){0.f, 0.f, 0.f, 0.f};

    float r[2][4];
    stage_load(W, k0, n0, N, K, ldw, tid, fast, r);
    stage_write(lds[0], tid, r);

    uintx4 bv[2][4];
    load_b4(bf, 0, bv[0]);
    if (KSTEPS > 1) load_b4(bf, 1, bv[1]);

    #pragma unroll
    for (int st = 0; st < KSTEPS; st++) {
        if (st + 1 < KSTEPS)
            stage_load(W, k0 + (st + 1) * 32, n0, N, K, ldw, tid, fast, r);
        uintx4 bt[4];
        if (st + 2 < KSTEPS) load_b4(bf, st + 2, bt);

        __syncthreads();                        // lds[st&1] writes visible

        const float* lb = lds[st & 1];
        short8 af;
        #pragma unroll
        for (int j = 0; j < 8; j++)
            af[j] = (short)f2bf(lb[(q * 8 + j) * 65 + 16 * w + l15]);

        const int p = st & 1;                   // compile-time after unroll
        #pragma unroll
        for (int s = 0; s < 4; s++) {
            short8 bf8 = __builtin_bit_cast(short8, bv[p][s]);
            acc[s] = __builtin_amdgcn_mfma_f32_16x16x32_bf16(af, bf8, acc[s], 0, 0, 0);
        }

        if (st + 1 < KSTEPS)
            stage_write(lds[(st + 1) & 1], tid, r);   // safe: prior reads of this buf done pre-barrier
        if (st + 2 < KSTEPS) {
            #pragma unroll
            for (int s = 0; s < 4; s++) bv[p][s] = bt[s];
        }
    }

    // D lane mapping: col=lane&15 (batch within group s), row=q*4+r (n offset)
    int nrow = n0 + 16 * w + q * 4;
    #pragma unroll
    for (int s = 0; s < 4; s++) {
        #pragma unroll
        for (int rr = 0; rr < 4; rr++)
            atomicAdd(&accbuf[(size_t)(nrow + rr) * 64 + s * 16 + l15], acc[s][rr]);
    }
}

// Node 2: GEMM1  h_pre += gos @ W1  (N=1500, K=10000)
__global__ __launch_bounds__(256) void gemm1_k(
    const float* __restrict__ W1, const unsigned short* __restrict__ gosBf,
    float* __restrict__ hpre)
{
    __shared__ float lds[2][LDSF];
    gemm_core<KST1>(W1, gosBf, hpre, HID, IN_SH, HID, blockIdx.x, blockIdx.y,
                    threadIdx.x, lds);
}

// Node 4: GEMM2  logits += X @ W2  (N=2048, K=1553)
__global__ __launch_bounds__(256) void gemm2_k(
    const float* __restrict__ W2, const unsigned short* __restrict__ Xf,
    float* __restrict__ logits)
{
    __shared__ float lds[2][LDSF];
    gemm_core<KST2>(W2, Xf, logits, NBC, K2, NBC, blockIdx.x, blockIdx.y,
                    threadIdx.x, lds);
}

// Node 3: bias + exact GELU on h_pre, concat exp_x, emit Xf in B-fragment order.
__global__ __launch_bounds__(256) void combine1(
    const float* __restrict__ hpre, const float* __restrict__ b1,
    const float* __restrict__ expx, unsigned short* __restrict__ Xf)
{
    int t    = blockIdx.x * 256 + threadIdx.x;   // [0, 13312)
    int lane = t & 63;
    int sgrp = (t >> 6) & 3;
    int step = t >> 8;                            // [0, 52)
    int q    = lane >> 4;
    int l15  = lane & 15;
    int b    = sgrp * 16 + l15;
    int kb   = step * 32 + q * 8;
    unsigned int o[4];
    #pragma unroll
    for (int i = 0; i < 4; i++) {
        unsigned int lohi[2];
        #pragma unroll
        for (int h = 0; h < 2; h++) {
            int n = kb + 2 * i + h;
            float v = 0.f;
            if (n < HID) {
                float s = hpre[(size_t)n * 64 + b] + b1[n];
                v = 0.5f * s * (1.0f + erff(s * 0.70710678118654752f));
            } else if (n < HID + EXP_SH) {
                v = expx[b * EXP_SH + (n - HID)];
            }
            lohi[h] = f2bf(v);
        }
        o[i] = lohi[0] | (lohi[1] << 16);
    }
    uintx4 v; v.x = o[0]; v.y = o[1]; v.z = o[2]; v.w = o[3];
    *(uintx4*)(Xf + (size_t)t * 8) = v;
}

// Node 5: bias + sigmoid on logits, multiply by column max (reduce 32 chunks)
__global__ __launch_bounds__(256) void final_k(
    const float* __restrict__ logits, const float* __restrict__ b2,
    const float* __restrict__ cm, float* __restrict__ out)
{
    int idx = blockIdx.x * 256 + threadIdx.x;   // 64*2048 threads
    int b = idx & 63;
    int j = idx >> 6;
    float s = logits[(size_t)j * 64 + b] + b2[j];
    float sig = 1.0f / (1.0f + expf(-s));
    float m = 0.f;
    #pragma unroll
    for (int c = 0; c < CMCH; c++) m = fmaxf(m, cm[c * NBC + j]);
    out[(size_t)b * NBC + j] = sig * m;
}

extern "C" void kernel_launch(void* const* d_in, const int* in_sizes, int n_in,
                              void* d_out, int out_size, void* d_ws, size_t ws_size,
                              hipStream_t stream) {
    const float* gos  = (const float*)d_in[0];
    const float* expx = (const float*)d_in[1];
    const float* W1   = (const float*)d_in[2];
    const float* b1   = (const float*)d_in[3];
    const float* W2   = (const float*)d_in[4];
    const float* b2   = (const float*)d_in[5];
    const float* hpo  = (const float*)d_in[6];
    float* out = (float*)d_out;

    // workspace layout (16B-aligned offsets)
    char* ws = (char*)d_ws;
    unsigned short* gosBf = (unsigned short*)ws;                   // 320*4*64*8*2 = 1,310,720
    float* hpre   = (float*)(ws + 1310720);                        // 1536*64*4    =   393,216
    float* logits = (float*)(ws + 1310720 + 393216);               // 2048*64*4    =   524,288 (contiguous with hpre)
    unsigned short* Xf = (unsigned short*)(ws + 1310720 + 393216 + 524288);  // 52*4*64*8*2 = 212,992
    float* cm = (float*)(ws + 1310720 + 393216 + 524288 + 212992); // 32*2048*4    =   262,144
    // total ~2.7 MB

    // 1) build gosBf | hpo partial column-max | zero accumulators
    prep_k<<<584, 256, 0, stream>>>(gos, gosBf, hpo, cm, hpre);

    // 2) GEMM1 (atomic split-K, LDS-staged W)
    gemm1_k<<<dim3(NPAD1 / 64, KS1), 256, 0, stream>>>(W1, gosBf, hpre);

    // 3) bias + gelu + concat exp_x -> Xf (B-fragment order)
    combine1<<<52, 256, 0, stream>>>(hpre, b1, expx, Xf);

    // 4) GEMM2 (atomic split-K, LDS-staged W)
    gemm2_k<<<dim3(NBC / 64, KS2), 256, 0, stream>>>(W2, Xf, logits);

    // 5) bias + sigmoid + *colmax -> out
    final_k<<<(B64 * NBC) / 256, 256, 0, stream>>>(logits, b2, cm, out);
}